// Round 2
// baseline (823.823 us; speedup 1.0000x reference)
//
#include <hip/hip_runtime.h>
#include <cstdint>

// Problem constants
#define BATCH 8
#define HGT 128
#define WID 128
#define CHN 256
#define HWID 65   // half-spectrum width (W/2+1)

typedef __attribute__((ext_vector_type(4))) float f32x4;
typedef __attribute__((ext_vector_type(8))) _Float16 f16x8;
typedef __attribute__((ext_vector_type(4))) _Float16 f16x4;
typedef __attribute__((ext_vector_type(2))) _Float16 h2c;   // complex fp16

__device__ __forceinline__ float2 cmulf(float2 a, float2 b) {
  return make_float2(fmaf(a.x, b.x, -a.y * b.y), fmaf(a.x, b.y, a.y * b.x));
}
__device__ __forceinline__ float2 h2f(h2c v) { return make_float2((float)v[0], (float)v[1]); }
__device__ __forceinline__ h2c f2h(float2 v) { h2c r; r[0] = (_Float16)v.x; r[1] = (_Float16)v.y; return r; }

// DIF butterfly: (a,b) -> (a+b, (a-b)*w)
__device__ __forceinline__ void bf_dif(float2& a, float2& b, float2 w) {
  float2 s = make_float2(a.x + b.x, a.y + b.y);
  float2 d = make_float2(a.x - b.x, a.y - b.y);
  a = s; b = cmulf(d, w);
}
// DIT butterfly: t=b*w; (a,b) -> (a+t, a-t)
__device__ __forceinline__ void bf_dit(float2& a, float2& b, float2 w) {
  float2 t = cmulf(b, w);
  b = make_float2(a.x - t.x, a.y - t.y);
  a = make_float2(a.x + t.x, a.y + t.y);
}

__device__ __forceinline__ void build_tw(float2* tw, int t) {
  if (t < 64) {
    float sn, cs;
    sincosf(-6.2831853071795864769f * (float)t / 128.0f, &sn, &cs);
    tw[t] = make_float2(cs, sn);
  }
}

// ---- register FFT, 128-pt, thread pp (0..7) of a channel holds 16 points ----
// Phase A (DIF stages d=64,32,16,8), regs r[k] = storage j = pp + 8k. Table twiddles.
template <int CONJ>
__device__ __forceinline__ void phaseA_dif(float2 r[16], const float2* tw, int pp) {
#pragma unroll
  for (int k = 0; k < 8; ++k) {                       // d=64
    float2 w = tw[pp + 8 * k]; if (CONJ) w.y = -w.y;
    bf_dif(r[k], r[k + 8], w);
  }
#pragma unroll
  for (int g = 0; g < 2; ++g)                         // d=32
#pragma unroll
    for (int k = 0; k < 4; ++k) {
      float2 w = tw[(pp + 8 * k) << 1]; if (CONJ) w.y = -w.y;
      bf_dif(r[g * 8 + k], r[g * 8 + k + 4], w);
    }
#pragma unroll
  for (int g = 0; g < 4; ++g)                         // d=16
#pragma unroll
    for (int k = 0; k < 2; ++k) {
      float2 w = tw[(pp + 8 * k) << 2]; if (CONJ) w.y = -w.y;
      bf_dif(r[g * 4 + k], r[g * 4 + k + 2], w);
    }
  {                                                   // d=8
    float2 w = tw[pp << 3]; if (CONJ) w.y = -w.y;
#pragma unroll
    for (int g = 0; g < 8; ++g) bf_dif(r[2 * g], r[2 * g + 1], w);
  }
}

// Phase B (DIF stages d=4,2,1), regs r[i] = storage j = 16*pp + i. Constant twiddles.
template <int CONJ>
__device__ __forceinline__ void phaseB_dif(float2 r[16]) {
  const float C = 0.70710678118654752f;
  const float S = CONJ ? 1.f : -1.f;
  float2 w1 = make_float2(1.f, 0.f);
  float2 w16 = make_float2(C, S * C);
  float2 w32 = make_float2(0.f, S);
  float2 w48 = make_float2(-C, S * C);
#pragma unroll
  for (int m = 0; m < 2; ++m) {                       // d=4
    int g = m * 8;
    bf_dif(r[g + 0], r[g + 4], w1);
    bf_dif(r[g + 1], r[g + 5], w16);
    bf_dif(r[g + 2], r[g + 6], w32);
    bf_dif(r[g + 3], r[g + 7], w48);
  }
#pragma unroll
  for (int q = 0; q < 4; ++q) {                       // d=2
    int g = q * 4;
    bf_dif(r[g + 0], r[g + 2], w1);
    bf_dif(r[g + 1], r[g + 3], w32);
  }
#pragma unroll
  for (int q = 0; q < 8; ++q) bf_dif(r[2 * q], r[2 * q + 1], w1);  // d=1
}

// Inverse phase B (DIT stages d=1,2,4), conj twiddles, regs = storage 16*pp+i.
__device__ __forceinline__ void phaseB_dit(float2 r[16]) {
  const float C = 0.70710678118654752f;
  float2 w1 = make_float2(1.f, 0.f);
  float2 w16 = make_float2(C, C);
  float2 w32 = make_float2(0.f, 1.f);
  float2 w48 = make_float2(-C, C);
#pragma unroll
  for (int q = 0; q < 8; ++q) bf_dit(r[2 * q], r[2 * q + 1], w1);  // d=1
#pragma unroll
  for (int q = 0; q < 4; ++q) {                       // d=2
    int g = q * 4;
    bf_dit(r[g + 0], r[g + 2], w1);
    bf_dit(r[g + 1], r[g + 3], w32);
  }
#pragma unroll
  for (int m = 0; m < 2; ++m) {                       // d=4
    int g = m * 8;
    bf_dit(r[g + 0], r[g + 4], w1);
    bf_dit(r[g + 1], r[g + 5], w16);
    bf_dit(r[g + 2], r[g + 6], w32);
    bf_dit(r[g + 3], r[g + 7], w48);
  }
}

// Inverse phase A (DIT stages d=8,16,32,64), conj table twiddles, regs = storage pp+8k.
__device__ __forceinline__ void phaseA_dit(float2 r[16], const float2* tw, int pp) {
  {                                                   // d=8
    float2 w = tw[pp << 3]; w.y = -w.y;
#pragma unroll
    for (int g = 0; g < 8; ++g) bf_dit(r[2 * g], r[2 * g + 1], w);
  }
#pragma unroll
  for (int g = 0; g < 4; ++g)                         // d=16
#pragma unroll
    for (int k = 0; k < 2; ++k) {
      float2 w = tw[(pp + 8 * k) << 2]; w.y = -w.y;
      bf_dit(r[g * 4 + k], r[g * 4 + k + 2], w);
    }
#pragma unroll
  for (int g = 0; g < 2; ++g)                         // d=32
#pragma unroll
    for (int k = 0; k < 4; ++k) {
      float2 w = tw[(pp + 8 * k) << 1]; w.y = -w.y;
      bf_dit(r[g * 8 + k], r[g * 8 + k + 4], w);
    }
#pragma unroll
  for (int k = 0; k < 8; ++k) {                       // d=64
    float2 w = tw[pp + 8 * k]; w.y = -w.y;
    bf_dit(r[k], r[k + 8], w);
  }
}

__device__ __forceinline__ void gload_lds16(const _Float16* g, _Float16* l) {
  __builtin_amdgcn_global_load_lds((const __attribute__((address_space(1))) unsigned int*)g,
                                   (__attribute__((address_space(3))) unsigned int*)l, 16, 0, 0);
}

// ---------------- weight packing: Wt[p=d*4+proj][k] fp16 ----------------
__global__ __launch_bounds__(256) void prep_w(const float* __restrict__ Wma, const float* __restrict__ Wpa,
                                              const float* __restrict__ Wmb, const float* __restrict__ Wpb,
                                              _Float16* __restrict__ Wt) {
  int k = blockIdx.x, d = threadIdx.x;
  Wt[(d * 4 + 0) * 256 + k] = (_Float16)Wma[k * 256 + d];
  Wt[(d * 4 + 1) * 256 + k] = (_Float16)Wpa[k * 256 + d];
  Wt[(d * 4 + 2) * 256 + k] = (_Float16)Wmb[k * 256 + d];
  Wt[(d * 4 + 3) * 256 + k] = (_Float16)Wpb[k * 256 + d];
}

// ---------------- kernel->freq, stage 1: DFT over j (7 taps) ----------------
__global__ __launch_bounds__(256) void kfreq1(const float* __restrict__ KA, const float* __restrict__ KB,
                                              float2* __restrict__ tA, float2* __restrict__ tB) {
  int i = blockIdx.x / HWID, v = blockIdx.x % HWID, c = threadIdx.x;
  const float w0 = -6.2831853071795864769f / 128.0f;
  float2 sa = make_float2(0.f, 0.f), sb = make_float2(0.f, 0.f);
#pragma unroll
  for (int j = 0; j < 7; ++j) {
    float ang = w0 * (float)(v * (j - 3));
    float sn, cs;
    sincosf(ang, &sn, &cs);
    float ka = KA[c * 49 + i * 7 + j];
    float kb = KB[c * 49 + i * 7 + j];
    sa.x = fmaf(ka, cs, sa.x); sa.y = fmaf(ka, sn, sa.y);
    sb.x = fmaf(kb, cs, sb.x); sb.y = fmaf(kb, sn, sb.y);
  }
  tA[(i * HWID + v) * 256 + c] = sa;
  tB[(i * HWID + v) * 256 + c] = sb;
}

// stage 2: DFT over i -> Af[u][v][c] fp16 complex (half-spectrum in v)
__global__ __launch_bounds__(256) void kfreq2(const float2* __restrict__ tA, const float2* __restrict__ tB,
                                              h2c* __restrict__ Af, h2c* __restrict__ Bf) {
  int u = blockIdx.x / HWID, v = blockIdx.x % HWID, c = threadIdx.x;
  const float w0 = -6.2831853071795864769f / 128.0f;
  float2 sa = make_float2(0.f, 0.f), sb = make_float2(0.f, 0.f);
#pragma unroll
  for (int i = 0; i < 7; ++i) {
    float ang = w0 * (float)(u * (i - 3));
    float sn, cs;
    sincosf(ang, &sn, &cs);
    float2 a = tA[(i * HWID + v) * 256 + c];
    float2 b = tB[(i * HWID + v) * 256 + c];
    sa.x += a.x * cs - a.y * sn; sa.y += a.x * sn + a.y * cs;
    sb.x += b.x * cs - b.y * sn; sb.y += b.x * sn + b.y * cs;
  }
  Af[(u * HWID + v) * 256 + c] = f2h(sa);
  Bf[(u * HWID + v) * 256 + c] = f2h(sb);
}

// ---------------- pass1: FFT over W (R2C half-spectrum), also emit fp16 x ----------------
__global__ __launch_bounds__(256) void pass1_fftw(const float* __restrict__ x, h2c* __restrict__ X1,
                                                  _Float16* __restrict__ xh) {
  __shared__ float2 Xs[128 * 32];
  __shared__ float2 tw[64];
  int t = threadIdx.x, cc = t & 31, pp = t >> 5;
  int c0 = blockIdx.x * 32, h = blockIdx.y, b = blockIdx.z;
  build_tw(tw, t);
  int base = ((b * HGT + h) * WID) * CHN + c0 + cc;
  float2 r[16];
#pragma unroll
  for (int k = 0; k < 16; ++k) {
    int w = pp + 8 * k;
    float v = x[base + w * CHN];
    xh[base + w * CHN] = (_Float16)v;
    r[k] = make_float2(v, 0.f);
  }
  __syncthreads();  // tw ready
  phaseA_dif<0>(r, tw, pp);
#pragma unroll
  for (int k = 0; k < 16; ++k) Xs[(pp + 8 * k) * 32 + cc] = r[k];
  __syncthreads();
#pragma unroll
  for (int i = 0; i < 16; ++i) r[i] = Xs[(16 * pp + i) * 32 + cc];
  phaseB_dif<0>(r);
  int obase = ((b * HGT + h) * HWID) * CHN + c0 + cc;
#pragma unroll
  for (int i = 0; i < 16; ++i) {
    int j = 16 * pp + i;
    int wt = __brev((unsigned)j) >> 25;
    if (wt < HWID) X1[obase + wt * CHN] = f2h(r[i]);
  }
}

// ---------------- GEMM (fp16 MFMA) + gate epilogue ----------------
__global__ __launch_bounds__(256) void gemm_gates(const _Float16* __restrict__ xh, const _Float16* __restrict__ Wt,
                                                  const float* __restrict__ bma, const float* __restrict__ bpa,
                                                  const float* __restrict__ bmb, const float* __restrict__ bpb,
                                                  _Float16* __restrict__ gates) {
  __shared__ alignas(16) char smem[33792];  // As 8KB | Bs 8KB; Cs (64x132 f32) overlays
  _Float16* As = (_Float16*)smem;
  _Float16* Bs = (_Float16*)(smem + 8192);
  float* Cs = (float*)smem;

  int t = threadIdx.x;
  int nblk = blockIdx.x, mblk = blockIdx.y;
  int m0 = mblk * 128, p0 = nblk * 128;
  int wv = t >> 6, lane = t & 63;
  int wm = wv >> 1, wn = wv & 1;
  int fr = lane & 15, fk = (lane >> 4) * 8;

  f32x4 acc[4][4] = {};
  const _Float16* Ag = xh + (size_t)m0 * 256;
  const _Float16* Bg = Wt + (size_t)p0 * 256;

  for (int kt = 0; kt < 8; ++kt) {
    int k0 = kt * 32;
#pragma unroll
    for (int iss = 0; iss < 2; ++iss) {
      int i = iss * 256 + t;
      gload_lds16(Ag + (i >> 2) * 256 + k0 + (i & 3) * 8, As + (iss * 256 + wv * 64) * 8);
      gload_lds16(Bg + (i >> 2) * 256 + k0 + (i & 3) * 8, Bs + (iss * 256 + wv * 64) * 8);
    }
    __syncthreads();
    f16x8 af[4], bf[4];
#pragma unroll
    for (int mi = 0; mi < 4; ++mi) af[mi] = *(const f16x8*)&As[(wm * 64 + mi * 16 + fr) * 32 + fk];
#pragma unroll
    for (int ni = 0; ni < 4; ++ni) bf[ni] = *(const f16x8*)&Bs[(wn * 64 + ni * 16 + fr) * 32 + fk];
#pragma unroll
    for (int mi = 0; mi < 4; ++mi)
#pragma unroll
      for (int ni = 0; ni < 4; ++ni)
        acc[mi][ni] = __builtin_amdgcn_mfma_f32_16x16x32_f16(af[mi], bf[ni], acc[mi][ni], 0, 0, 0);
    __syncthreads();
  }

  int cl = t & 31;
  int c = nblk * 32 + cl;
  float vbma = bma[c], vbpa = bpa[c], vbmb = bmb[c], vbpb = bpb[c];

  for (int halfr = 0; halfr < 2; ++halfr) {
    if (wm == halfr) {
#pragma unroll
      for (int mi = 0; mi < 4; ++mi)
#pragma unroll
        for (int ni = 0; ni < 4; ++ni)
#pragma unroll
          for (int r = 0; r < 4; ++r)
            Cs[(mi * 16 + (lane >> 4) * 4 + r) * 132 + wn * 64 + ni * 16 + (lane & 15)] = acc[mi][ni][r];
    }
    __syncthreads();
#pragma unroll
    for (int it = 0; it < 8; ++it) {
      int rl = (t >> 5) + it * 8;
      float4 y = *(const float4*)&Cs[rl * 132 + cl * 4];
      float sa = 1.f / (1.f + __expf(-(y.x + vbma)));
      float sb = 1.f / (1.f + __expf(-(y.z + vbmb)));
      float sna, csa, snb, csb;
      __sincosf(y.y + vbpa, &sna, &csa);
      __sincosf(y.w + vbpb, &snb, &csb);
      int m = m0 + halfr * 64 + rl;
      f16x4 g;
      g[0] = (_Float16)(sa * csa); g[1] = (_Float16)(sa * sna);
      g[2] = (_Float16)(sb * csb); g[3] = (_Float16)(sb * snb);
      *(f16x4*)&gates[(size_t)m * 1024 + c * 4] = g;
    }
    __syncthreads();
  }
}

// ---------------- pass2: per column w<=64: FFT_H, pointwise G_herm*x_f, IFFT_H (in place) --------
__global__ __launch_bounds__(256) void pass2_col(h2c* __restrict__ X1, const _Float16* __restrict__ gates,
                                                 const h2c* __restrict__ Af, const h2c* __restrict__ Bf) {
  __shared__ float2 Xs[128 * 32];
  __shared__ float2 tw[64];
  int t = threadIdx.x, cc = t & 31, pp = t >> 5;
  int c0 = blockIdx.x * 32, w = blockIdx.y, b = blockIdx.z;
  build_tw(tw, t);
  int colbase = ((b * HGT) * HWID + w) * CHN + c0 + cc;  // + h*HWID*CHN
  float2 r[16];
#pragma unroll
  for (int k = 0; k < 16; ++k) r[k] = h2f(X1[colbase + (pp + 8 * k) * HWID * CHN]);
  __syncthreads();  // tw ready
  phaseA_dif<0>(r, tw, pp);
#pragma unroll
  for (int k = 0; k < 16; ++k) Xs[(pp + 8 * k) * 32 + cc] = r[k];
  __syncthreads();
#pragma unroll
  for (int i = 0; i < 16; ++i) r[i] = Xs[(16 * pp + i) * 32 + cc];
  phaseB_dif<0>(r);
  // pointwise at storage j = 16*pp + i, frequency u = rev7(j)
  int wp = (128 - w) & 127;
  const float sc = 0.5f / 128.0f;  // half of Hermitian-fold; other 1/128 applied in pass3
#pragma unroll 4
  for (int i = 0; i < 16; ++i) {
    int j = 16 * pp + i;
    int u = __brev((unsigned)j) >> 25;
    int up = (128 - u) & 127;
    int gidx1 = (((b * HGT + u) * WID + w) * CHN + c0 + cc) * 4;
    int gidx2 = (((b * HGT + up) * WID + wp) * CHN + c0 + cc) * 4;
    f16x4 g1 = *(const f16x4*)&gates[gidx1];
    f16x4 g2 = *(const f16x4*)&gates[gidx2];
    int aidx = (u * HWID + w) * CHN + c0 + cc;
    float2 A1 = h2f(Af[aidx]);
    float2 B1 = h2f(Bf[aidx]);
    // bin (u,w)
    float2 a1 = cmulf(make_float2((float)g1[0], (float)g1[1]), A1);
    float2 S1 = make_float2(a1.x + 1.f, a1.y);
#pragma unroll
    for (int q = 0; q < 6; ++q) { S1 = cmulf(a1, S1); S1.x += 1.f; }
    float2 G1 = cmulf(cmulf(make_float2((float)g1[2], (float)g1[3]), B1), S1);
    // partner bin (-u,-w): Af/Bf conj (real kernels)
    float2 A2 = make_float2(A1.x, -A1.y), B2 = make_float2(B1.x, -B1.y);
    float2 a2 = cmulf(make_float2((float)g2[0], (float)g2[1]), A2);
    float2 S2 = make_float2(a2.x + 1.f, a2.y);
#pragma unroll
    for (int q = 0; q < 6; ++q) { S2 = cmulf(a2, S2); S2.x += 1.f; }
    float2 G2 = cmulf(cmulf(make_float2((float)g2[2], (float)g2[3]), B2), S2);
    float2 Gh = make_float2((G1.x + G2.x) * sc, (G1.y - G2.y) * sc);
    r[i] = cmulf(r[i], Gh);
  }
  phaseB_dit(r);
  __syncthreads();  // all reads of fwd transpose done before rewrite
#pragma unroll
  for (int i = 0; i < 16; ++i) Xs[(16 * pp + i) * 32 + cc] = r[i];
  __syncthreads();
#pragma unroll
  for (int k = 0; k < 16; ++k) r[k] = Xs[(pp + 8 * k) * 32 + cc];
  phaseA_dit(r, tw, pp);
#pragma unroll
  for (int k = 0; k < 16; ++k) X1[colbase + (pp + 8 * k) * HWID * CHN] = f2h(r[k]);
}

// ---------------- pass3: Hermitian-complete + inverse FFT over W, write real ----------------
__global__ __launch_bounds__(256) void pass3_ifftw(const h2c* __restrict__ X1, float* __restrict__ out) {
  __shared__ float2 Xs[128 * 32];
  __shared__ float2 tw[64];
  int t = threadIdx.x, cc = t & 31, pp = t >> 5;
  int c0 = blockIdx.x * 32, h = blockIdx.y, b = blockIdx.z;
  build_tw(tw, t);
  int rowbase = ((b * HGT + h) * HWID) * CHN + c0 + cc;
#pragma unroll
  for (int k = 0; k < 9; ++k) {
    int w = pp + 8 * k;
    if (w < HWID) Xs[w * 32 + cc] = h2f(X1[rowbase + w * CHN]);
  }
  __syncthreads();
  float2 r[16];
#pragma unroll
  for (int k = 0; k < 16; ++k) {
    int w = pp + 8 * k;
    if (w <= 64) {
      r[k] = Xs[w * 32 + cc];
    } else {
      float2 v = Xs[(128 - w) * 32 + cc];
      r[k] = make_float2(v.x, -v.y);
    }
  }
  phaseA_dif<1>(r, tw, pp);  // inverse (conj twiddles), unscaled
  __syncthreads();           // completion reads done before transpose write
#pragma unroll
  for (int k = 0; k < 16; ++k) Xs[(pp + 8 * k) * 32 + cc] = r[k];
  __syncthreads();
#pragma unroll
  for (int i = 0; i < 16; ++i) r[i] = Xs[(16 * pp + i) * 32 + cc];
  phaseB_dif<1>(r);
  int obase = ((b * HGT + h) * WID) * CHN + c0 + cc;
  const float fsc = 1.0f / 128.0f;
#pragma unroll
  for (int i = 0; i < 16; ++i) {
    int j = 16 * pp + i;
    int wt = __brev((unsigned)j) >> 25;
    out[obase + wt * CHN] = r[i].x * fsc;
  }
}

extern "C" void kernel_launch(void* const* d_in, const int* in_sizes, int n_in,
                              void* d_out, int out_size, void* d_ws, size_t ws_size,
                              hipStream_t stream) {
  (void)in_sizes; (void)n_in; (void)out_size;
  const float* x   = (const float*)d_in[0];
  const float* KA  = (const float*)d_in[1];
  const float* KB  = (const float*)d_in[2];
  const float* Wma = (const float*)d_in[3];
  const float* bma = (const float*)d_in[4];
  const float* Wpa = (const float*)d_in[5];
  const float* bpa = (const float*)d_in[6];
  const float* Wmb = (const float*)d_in[7];
  const float* bmb = (const float*)d_in[8];
  const float* Wpb = (const float*)d_in[9];
  const float* bpb = (const float*)d_in[10];
  float* out = (float*)d_out;

  char* ws = (char*)d_ws;
  size_t off = 0;
  auto alloc = [&](size_t bytes) -> char* {
    char* p = ws + off;
    off += (bytes + 255) & ~(size_t)255;
    return p;
  };
  const size_t M = (size_t)BATCH * HGT * WID;              // 131072 rows
  _Float16* Wt    = (_Float16*)alloc(1024 * 256 * 2);
  _Float16* xh    = (_Float16*)alloc(M * CHN * 2);
  _Float16* gates = (_Float16*)alloc(M * CHN * 4 * 2);
  h2c*      X1    = (h2c*)alloc((size_t)BATCH * HGT * HWID * CHN * 4);
  h2c*      Af    = (h2c*)alloc((size_t)HGT * HWID * CHN * 4);
  h2c*      Bf    = (h2c*)alloc((size_t)HGT * HWID * CHN * 4);
  float2*   tA    = (float2*)alloc((size_t)7 * HWID * CHN * 8);
  float2*   tB    = (float2*)alloc((size_t)7 * HWID * CHN * 8);
  if (off > ws_size) return;  // workspace too small: leaves output zero (diagnostic)

  prep_w<<<dim3(256), dim3(256), 0, stream>>>(Wma, Wpa, Wmb, Wpb, Wt);
  kfreq1<<<dim3(7 * HWID), dim3(256), 0, stream>>>(KA, KB, tA, tB);
  kfreq2<<<dim3(128 * HWID), dim3(256), 0, stream>>>(tA, tB, Af, Bf);
  pass1_fftw<<<dim3(CHN / 32, HGT, BATCH), dim3(256), 0, stream>>>(x, X1, xh);
  gemm_gates<<<dim3(8, 1024), dim3(256), 0, stream>>>(xh, Wt, bma, bpa, bmb, bpb, gates);
  pass2_col<<<dim3(CHN / 32, HWID, BATCH), dim3(256), 0, stream>>>(X1, gates, Af, Bf);
  pass3_ifftw<<<dim3(CHN / 32, HGT, BATCH), dim3(256), 0, stream>>>(X1, out);
}

// Round 3
// 610.799 us; speedup vs baseline: 1.3488x; 1.3488x over previous
//
#include <hip/hip_runtime.h>
#include <cstdint>

// Problem constants
#define BATCH 8
#define HGT 128
#define WID 128
#define CHN 256
#define HWID 65   // half-spectrum width (W/2+1)

typedef __attribute__((ext_vector_type(4))) float f32x4;
typedef __attribute__((ext_vector_type(8))) _Float16 f16x8;
typedef __attribute__((ext_vector_type(4))) _Float16 f16x4;
typedef __attribute__((ext_vector_type(2))) _Float16 h2c;   // complex fp16

__device__ __forceinline__ float2 cmulf(float2 a, float2 b) {
  return make_float2(fmaf(a.x, b.x, -a.y * b.y), fmaf(a.x, b.y, a.y * b.x));
}
__device__ __forceinline__ float2 h2f(h2c v) { return make_float2((float)v[0], (float)v[1]); }
__device__ __forceinline__ h2c f2h(float2 v) { h2c r; r[0] = (_Float16)v.x; r[1] = (_Float16)v.y; return r; }

// DIF butterfly: (a,b) -> (a+b, (a-b)*w)
__device__ __forceinline__ void bf_dif(float2& a, float2& b, float2 w) {
  float2 s = make_float2(a.x + b.x, a.y + b.y);
  float2 d = make_float2(a.x - b.x, a.y - b.y);
  a = s; b = cmulf(d, w);
}
// DIT butterfly: t=b*w; (a,b) -> (a+t, a-t)
__device__ __forceinline__ void bf_dit(float2& a, float2& b, float2 w) {
  float2 t = cmulf(b, w);
  b = make_float2(a.x - t.x, a.y - t.y);
  a = make_float2(a.x + t.x, a.y + t.y);
}

__device__ __forceinline__ void build_tw(float2* tw, int t) {
  if (t < 64) {
    float sn, cs;
    sincosf(-6.2831853071795864769f * (float)t / 128.0f, &sn, &cs);
    tw[t] = make_float2(cs, sn);
  }
}

// ---- register FFT, 128-pt, thread pp (0..7) of a channel holds 16 points ----
// Phase A (DIF stages d=64,32,16,8), regs r[k] = storage j = pp + 8k. Table twiddles.
template <int CONJ>
__device__ __forceinline__ void phaseA_dif(float2 r[16], const float2* tw, int pp) {
#pragma unroll
  for (int k = 0; k < 8; ++k) {                       // d=64
    float2 w = tw[pp + 8 * k]; if (CONJ) w.y = -w.y;
    bf_dif(r[k], r[k + 8], w);
  }
#pragma unroll
  for (int g = 0; g < 2; ++g)                         // d=32
#pragma unroll
    for (int k = 0; k < 4; ++k) {
      float2 w = tw[(pp + 8 * k) << 1]; if (CONJ) w.y = -w.y;
      bf_dif(r[g * 8 + k], r[g * 8 + k + 4], w);
    }
#pragma unroll
  for (int g = 0; g < 4; ++g)                         // d=16
#pragma unroll
    for (int k = 0; k < 2; ++k) {
      float2 w = tw[(pp + 8 * k) << 2]; if (CONJ) w.y = -w.y;
      bf_dif(r[g * 4 + k], r[g * 4 + k + 2], w);
    }
  {                                                   // d=8
    float2 w = tw[pp << 3]; if (CONJ) w.y = -w.y;
#pragma unroll
    for (int g = 0; g < 8; ++g) bf_dif(r[2 * g], r[2 * g + 1], w);
  }
}

// Phase B (DIF stages d=4,2,1), regs r[i] = storage j = 16*pp + i. Constant twiddles.
template <int CONJ>
__device__ __forceinline__ void phaseB_dif(float2 r[16]) {
  const float C = 0.70710678118654752f;
  const float S = CONJ ? 1.f : -1.f;
  float2 w1 = make_float2(1.f, 0.f);
  float2 w16 = make_float2(C, S * C);
  float2 w32 = make_float2(0.f, S);
  float2 w48 = make_float2(-C, S * C);
#pragma unroll
  for (int m = 0; m < 2; ++m) {                       // d=4
    int g = m * 8;
    bf_dif(r[g + 0], r[g + 4], w1);
    bf_dif(r[g + 1], r[g + 5], w16);
    bf_dif(r[g + 2], r[g + 6], w32);
    bf_dif(r[g + 3], r[g + 7], w48);
  }
#pragma unroll
  for (int q = 0; q < 4; ++q) {                       // d=2
    int g = q * 4;
    bf_dif(r[g + 0], r[g + 2], w1);
    bf_dif(r[g + 1], r[g + 3], w32);
  }
#pragma unroll
  for (int q = 0; q < 8; ++q) bf_dif(r[2 * q], r[2 * q + 1], w1);  // d=1
}

// Inverse phase B (DIT stages d=1,2,4), conj twiddles, regs = storage 16*pp+i.
__device__ __forceinline__ void phaseB_dit(float2 r[16]) {
  const float C = 0.70710678118654752f;
  float2 w1 = make_float2(1.f, 0.f);
  float2 w16 = make_float2(C, C);
  float2 w32 = make_float2(0.f, 1.f);
  float2 w48 = make_float2(-C, C);
#pragma unroll
  for (int q = 0; q < 8; ++q) bf_dit(r[2 * q], r[2 * q + 1], w1);  // d=1
#pragma unroll
  for (int q = 0; q < 4; ++q) {                       // d=2
    int g = q * 4;
    bf_dit(r[g + 0], r[g + 2], w1);
    bf_dit(r[g + 1], r[g + 3], w32);
  }
#pragma unroll
  for (int m = 0; m < 2; ++m) {                       // d=4
    int g = m * 8;
    bf_dit(r[g + 0], r[g + 4], w1);
    bf_dit(r[g + 1], r[g + 5], w16);
    bf_dit(r[g + 2], r[g + 6], w32);
    bf_dit(r[g + 3], r[g + 7], w48);
  }
}

// Inverse phase A (DIT stages d=8,16,32,64), conj table twiddles, regs = storage pp+8k.
__device__ __forceinline__ void phaseA_dit(float2 r[16], const float2* tw, int pp) {
  {                                                   // d=8
    float2 w = tw[pp << 3]; w.y = -w.y;
#pragma unroll
    for (int g = 0; g < 8; ++g) bf_dit(r[2 * g], r[2 * g + 1], w);
  }
#pragma unroll
  for (int g = 0; g < 4; ++g)                         // d=16
#pragma unroll
    for (int k = 0; k < 2; ++k) {
      float2 w = tw[(pp + 8 * k) << 2]; w.y = -w.y;
      bf_dit(r[g * 4 + k], r[g * 4 + k + 2], w);
    }
#pragma unroll
  for (int g = 0; g < 2; ++g)                         // d=32
#pragma unroll
    for (int k = 0; k < 4; ++k) {
      float2 w = tw[(pp + 8 * k) << 1]; w.y = -w.y;
      bf_dit(r[g * 8 + k], r[g * 8 + k + 4], w);
    }
#pragma unroll
  for (int k = 0; k < 8; ++k) {                       // d=64
    float2 w = tw[pp + 8 * k]; w.y = -w.y;
    bf_dit(r[k], r[k + 8], w);
  }
}

__device__ __forceinline__ void gload_lds16(const _Float16* g, _Float16* l) {
  __builtin_amdgcn_global_load_lds((const __attribute__((address_space(1))) unsigned int*)g,
                                   (__attribute__((address_space(3))) unsigned int*)l, 16, 0, 0);
}

// ---------------- weight packing: Wt[p=d*4+proj][k] fp16 ----------------
__global__ __launch_bounds__(256) void prep_w(const float* __restrict__ Wma, const float* __restrict__ Wpa,
                                              const float* __restrict__ Wmb, const float* __restrict__ Wpb,
                                              _Float16* __restrict__ Wt) {
  int k = blockIdx.x, d = threadIdx.x;
  Wt[(d * 4 + 0) * 256 + k] = (_Float16)Wma[k * 256 + d];
  Wt[(d * 4 + 1) * 256 + k] = (_Float16)Wpa[k * 256 + d];
  Wt[(d * 4 + 2) * 256 + k] = (_Float16)Wmb[k * 256 + d];
  Wt[(d * 4 + 3) * 256 + k] = (_Float16)Wpb[k * 256 + d];
}

// ---------------- kernel->freq, stage 1: DFT over j (7 taps) ----------------
__global__ __launch_bounds__(256) void kfreq1(const float* __restrict__ KA, const float* __restrict__ KB,
                                              float2* __restrict__ tA, float2* __restrict__ tB) {
  int i = blockIdx.x / HWID, v = blockIdx.x % HWID, c = threadIdx.x;
  const float w0 = -6.2831853071795864769f / 128.0f;
  float2 sa = make_float2(0.f, 0.f), sb = make_float2(0.f, 0.f);
#pragma unroll
  for (int j = 0; j < 7; ++j) {
    float ang = w0 * (float)(v * (j - 3));
    float sn, cs;
    sincosf(ang, &sn, &cs);
    float ka = KA[c * 49 + i * 7 + j];
    float kb = KB[c * 49 + i * 7 + j];
    sa.x = fmaf(ka, cs, sa.x); sa.y = fmaf(ka, sn, sa.y);
    sb.x = fmaf(kb, cs, sb.x); sb.y = fmaf(kb, sn, sb.y);
  }
  tA[(i * HWID + v) * 256 + c] = sa;
  tB[(i * HWID + v) * 256 + c] = sb;
}

// stage 2: DFT over i -> Af[u][v][c] fp16 complex (half-spectrum in v)
__global__ __launch_bounds__(256) void kfreq2(const float2* __restrict__ tA, const float2* __restrict__ tB,
                                              h2c* __restrict__ Af, h2c* __restrict__ Bf) {
  int u = blockIdx.x / HWID, v = blockIdx.x % HWID, c = threadIdx.x;
  const float w0 = -6.2831853071795864769f / 128.0f;
  float2 sa = make_float2(0.f, 0.f), sb = make_float2(0.f, 0.f);
#pragma unroll
  for (int i = 0; i < 7; ++i) {
    float ang = w0 * (float)(u * (i - 3));
    float sn, cs;
    sincosf(ang, &sn, &cs);
    float2 a = tA[(i * HWID + v) * 256 + c];
    float2 b = tB[(i * HWID + v) * 256 + c];
    sa.x += a.x * cs - a.y * sn; sa.y += a.x * sn + a.y * cs;
    sb.x += b.x * cs - b.y * sn; sb.y += b.x * sn + b.y * cs;
  }
  Af[(u * HWID + v) * 256 + c] = f2h(sa);
  Bf[(u * HWID + v) * 256 + c] = f2h(sb);
}

// ---------------- pass1: FFT over W (R2C half-spectrum), also emit fp16 x ----------------
__global__ __launch_bounds__(256) void pass1_fftw(const float* __restrict__ x, h2c* __restrict__ X1,
                                                  _Float16* __restrict__ xh) {
  __shared__ float2 Xs[128 * 32];
  __shared__ float2 tw[64];
  int t = threadIdx.x, cc = t & 31, pp = t >> 5;
  int c0 = blockIdx.x * 32, h = blockIdx.y, b = blockIdx.z;
  build_tw(tw, t);
  int base = ((b * HGT + h) * WID) * CHN + c0 + cc;
  float2 r[16];
#pragma unroll
  for (int k = 0; k < 16; ++k) {
    int w = pp + 8 * k;
    float v = x[base + w * CHN];
    xh[base + w * CHN] = (_Float16)v;
    r[k] = make_float2(v, 0.f);
  }
  __syncthreads();  // tw ready
  phaseA_dif<0>(r, tw, pp);
#pragma unroll
  for (int k = 0; k < 16; ++k) Xs[(pp + 8 * k) * 32 + cc] = r[k];
  __syncthreads();
#pragma unroll
  for (int i = 0; i < 16; ++i) r[i] = Xs[(16 * pp + i) * 32 + cc];
  phaseB_dif<0>(r);
  int obase = ((b * HGT + h) * HWID) * CHN + c0 + cc;
#pragma unroll
  for (int i = 0; i < 16; ++i) {
    int j = 16 * pp + i;
    int wt = __brev((unsigned)j) >> 25;
    if (wt < HWID) X1[obase + wt * CHN] = f2h(r[i]);
  }
}

// ---------------- GEMM (fp16 MFMA) + gate epilogue ----------------
__global__ __launch_bounds__(256) void gemm_gates(const _Float16* __restrict__ xh, const _Float16* __restrict__ Wt,
                                                  const float* __restrict__ bma, const float* __restrict__ bpa,
                                                  const float* __restrict__ bmb, const float* __restrict__ bpb,
                                                  _Float16* __restrict__ gates) {
  __shared__ alignas(16) char smem[33792];  // As 8KB | Bs 8KB; Cs (64x132 f32) overlays
  _Float16* As = (_Float16*)smem;
  _Float16* Bs = (_Float16*)(smem + 8192);
  float* Cs = (float*)smem;

  int t = threadIdx.x;
  int nblk = blockIdx.x, mblk = blockIdx.y;
  int m0 = mblk * 128, p0 = nblk * 128;
  int wv = t >> 6, lane = t & 63;
  int wm = wv >> 1, wn = wv & 1;
  int fr = lane & 15, fk = (lane >> 4) * 8;

  f32x4 acc[4][4] = {};
  const _Float16* Ag = xh + (size_t)m0 * 256;
  const _Float16* Bg = Wt + (size_t)p0 * 256;

  for (int kt = 0; kt < 8; ++kt) {
    int k0 = kt * 32;
#pragma unroll
    for (int iss = 0; iss < 2; ++iss) {
      int i = iss * 256 + t;
      gload_lds16(Ag + (i >> 2) * 256 + k0 + (i & 3) * 8, As + (iss * 256 + wv * 64) * 8);
      gload_lds16(Bg + (i >> 2) * 256 + k0 + (i & 3) * 8, Bs + (iss * 256 + wv * 64) * 8);
    }
    __syncthreads();
    f16x8 af[4], bf[4];
#pragma unroll
    for (int mi = 0; mi < 4; ++mi) af[mi] = *(const f16x8*)&As[(wm * 64 + mi * 16 + fr) * 32 + fk];
#pragma unroll
    for (int ni = 0; ni < 4; ++ni) bf[ni] = *(const f16x8*)&Bs[(wn * 64 + ni * 16 + fr) * 32 + fk];
#pragma unroll
    for (int mi = 0; mi < 4; ++mi)
#pragma unroll
      for (int ni = 0; ni < 4; ++ni)
        acc[mi][ni] = __builtin_amdgcn_mfma_f32_16x16x32_f16(af[mi], bf[ni], acc[mi][ni], 0, 0, 0);
    __syncthreads();
  }

  int cl = t & 31;
  int c = nblk * 32 + cl;
  float vbma = bma[c], vbpa = bpa[c], vbmb = bmb[c], vbpb = bpb[c];

  for (int halfr = 0; halfr < 2; ++halfr) {
    if (wm == halfr) {
#pragma unroll
      for (int mi = 0; mi < 4; ++mi)
#pragma unroll
        for (int ni = 0; ni < 4; ++ni)
#pragma unroll
          for (int r = 0; r < 4; ++r)
            Cs[(mi * 16 + (lane >> 4) * 4 + r) * 132 + wn * 64 + ni * 16 + (lane & 15)] = acc[mi][ni][r];
    }
    __syncthreads();
#pragma unroll
    for (int it = 0; it < 8; ++it) {
      int rl = (t >> 5) + it * 8;
      float4 y = *(const float4*)&Cs[rl * 132 + cl * 4];
      float sa = 1.f / (1.f + __expf(-(y.x + vbma)));
      float sb = 1.f / (1.f + __expf(-(y.z + vbmb)));
      float sna, csa, snb, csb;
      __sincosf(y.y + vbpa, &sna, &csa);
      __sincosf(y.w + vbpb, &snb, &csb);
      int m = m0 + halfr * 64 + rl;
      f16x4 g;
      g[0] = (_Float16)(sa * csa); g[1] = (_Float16)(sa * sna);
      g[2] = (_Float16)(sb * csb); g[3] = (_Float16)(sb * snb);
      *(f16x4*)&gates[(size_t)m * 1024 + c * 4] = g;
    }
    __syncthreads();
  }
}

// ---------------- pass2: per column w<=64: FFT_H, pointwise G_herm*x_f, IFFT_H (in place) --------
__global__ __launch_bounds__(256) void pass2_col(h2c* __restrict__ X1, const _Float16* __restrict__ gates,
                                                 const h2c* __restrict__ Af, const h2c* __restrict__ Bf) {
  __shared__ float2 Xs[128 * 32];
  __shared__ float2 tw[64];
  int t = threadIdx.x, cc = t & 31, pp = t >> 5;
  int c0 = blockIdx.x * 32, w = blockIdx.y, b = blockIdx.z;
  build_tw(tw, t);
  int colbase = ((b * HGT) * HWID + w) * CHN + c0 + cc;  // + h*HWID*CHN
  float2 r[16];
#pragma unroll
  for (int k = 0; k < 16; ++k) r[k] = h2f(X1[colbase + (pp + 8 * k) * HWID * CHN]);
  __syncthreads();  // tw ready
  phaseA_dif<0>(r, tw, pp);
#pragma unroll
  for (int k = 0; k < 16; ++k) Xs[(pp + 8 * k) * 32 + cc] = r[k];
  __syncthreads();
#pragma unroll
  for (int i = 0; i < 16; ++i) r[i] = Xs[(16 * pp + i) * 32 + cc];
  phaseB_dif<0>(r);
  // pointwise at storage j = 16*pp + i, frequency u = rev7(j).
  // MUST be fully unrolled: partial unroll makes r[i] dynamically indexed ->
  // the whole r[16] array spills to scratch (R1: VGPR 52, +600 MB HBM writes).
  int wp = (128 - w) & 127;
  const float sc = 0.5f / 128.0f;  // half of Hermitian-fold; other 1/128 applied in pass3
#pragma unroll
  for (int i = 0; i < 16; ++i) {
    int j = 16 * pp + i;
    int u = __brev((unsigned)j) >> 25;
    int up = (128 - u) & 127;
    int gidx1 = (((b * HGT + u) * WID + w) * CHN + c0 + cc) * 4;
    int gidx2 = (((b * HGT + up) * WID + wp) * CHN + c0 + cc) * 4;
    f16x4 g1 = *(const f16x4*)&gates[gidx1];
    f16x4 g2 = *(const f16x4*)&gates[gidx2];
    int aidx = (u * HWID + w) * CHN + c0 + cc;
    float2 A1 = h2f(Af[aidx]);
    float2 B1 = h2f(Bf[aidx]);
    // bin (u,w)
    float2 a1 = cmulf(make_float2((float)g1[0], (float)g1[1]), A1);
    float2 S1 = make_float2(a1.x + 1.f, a1.y);
#pragma unroll
    for (int q = 0; q < 6; ++q) { S1 = cmulf(a1, S1); S1.x += 1.f; }
    float2 G1 = cmulf(cmulf(make_float2((float)g1[2], (float)g1[3]), B1), S1);
    // partner bin (-u,-w): Af/Bf conj (real kernels)
    float2 A2 = make_float2(A1.x, -A1.y), B2 = make_float2(B1.x, -B1.y);
    float2 a2 = cmulf(make_float2((float)g2[0], (float)g2[1]), A2);
    float2 S2 = make_float2(a2.x + 1.f, a2.y);
#pragma unroll
    for (int q = 0; q < 6; ++q) { S2 = cmulf(a2, S2); S2.x += 1.f; }
    float2 G2 = cmulf(cmulf(make_float2((float)g2[2], (float)g2[3]), B2), S2);
    float2 Gh = make_float2((G1.x + G2.x) * sc, (G1.y - G2.y) * sc);
    r[i] = cmulf(r[i], Gh);
  }
  phaseB_dit(r);
  __syncthreads();  // all reads of fwd transpose done before rewrite
#pragma unroll
  for (int i = 0; i < 16; ++i) Xs[(16 * pp + i) * 32 + cc] = r[i];
  __syncthreads();
#pragma unroll
  for (int k = 0; k < 16; ++k) r[k] = Xs[(pp + 8 * k) * 32 + cc];
  phaseA_dit(r, tw, pp);
#pragma unroll
  for (int k = 0; k < 16; ++k) X1[colbase + (pp + 8 * k) * HWID * CHN] = f2h(r[k]);
}

// ---------------- pass3: Hermitian-complete + inverse FFT over W, write real ----------------
__global__ __launch_bounds__(256) void pass3_ifftw(const h2c* __restrict__ X1, float* __restrict__ out) {
  __shared__ float2 Xs[128 * 32];
  __shared__ float2 tw[64];
  int t = threadIdx.x, cc = t & 31, pp = t >> 5;
  int c0 = blockIdx.x * 32, h = blockIdx.y, b = blockIdx.z;
  build_tw(tw, t);
  int rowbase = ((b * HGT + h) * HWID) * CHN + c0 + cc;
#pragma unroll
  for (int k = 0; k < 9; ++k) {
    int w = pp + 8 * k;
    if (w < HWID) Xs[w * 32 + cc] = h2f(X1[rowbase + w * CHN]);
  }
  __syncthreads();
  float2 r[16];
#pragma unroll
  for (int k = 0; k < 16; ++k) {
    int w = pp + 8 * k;
    if (w <= 64) {
      r[k] = Xs[w * 32 + cc];
    } else {
      float2 v = Xs[(128 - w) * 32 + cc];
      r[k] = make_float2(v.x, -v.y);
    }
  }
  phaseA_dif<1>(r, tw, pp);  // inverse (conj twiddles), unscaled
  __syncthreads();           // completion reads done before transpose write
#pragma unroll
  for (int k = 0; k < 16; ++k) Xs[(pp + 8 * k) * 32 + cc] = r[k];
  __syncthreads();
#pragma unroll
  for (int i = 0; i < 16; ++i) r[i] = Xs[(16 * pp + i) * 32 + cc];
  phaseB_dif<1>(r);
  int obase = ((b * HGT + h) * WID) * CHN + c0 + cc;
  const float fsc = 1.0f / 128.0f;
#pragma unroll
  for (int i = 0; i < 16; ++i) {
    int j = 16 * pp + i;
    int wt = __brev((unsigned)j) >> 25;
    out[obase + wt * CHN] = r[i].x * fsc;
  }
}

extern "C" void kernel_launch(void* const* d_in, const int* in_sizes, int n_in,
                              void* d_out, int out_size, void* d_ws, size_t ws_size,
                              hipStream_t stream) {
  (void)in_sizes; (void)n_in; (void)out_size;
  const float* x   = (const float*)d_in[0];
  const float* KA  = (const float*)d_in[1];
  const float* KB  = (const float*)d_in[2];
  const float* Wma = (const float*)d_in[3];
  const float* bma = (const float*)d_in[4];
  const float* Wpa = (const float*)d_in[5];
  const float* bpa = (const float*)d_in[6];
  const float* Wmb = (const float*)d_in[7];
  const float* bmb = (const float*)d_in[8];
  const float* Wpb = (const float*)d_in[9];
  const float* bpb = (const float*)d_in[10];
  float* out = (float*)d_out;

  char* ws = (char*)d_ws;
  size_t off = 0;
  auto alloc = [&](size_t bytes) -> char* {
    char* p = ws + off;
    off += (bytes + 255) & ~(size_t)255;
    return p;
  };
  const size_t M = (size_t)BATCH * HGT * WID;              // 131072 rows
  _Float16* Wt    = (_Float16*)alloc(1024 * 256 * 2);
  _Float16* xh    = (_Float16*)alloc(M * CHN * 2);
  _Float16* gates = (_Float16*)alloc(M * CHN * 4 * 2);
  h2c*      X1    = (h2c*)alloc((size_t)BATCH * HGT * HWID * CHN * 4);
  h2c*      Af    = (h2c*)alloc((size_t)HGT * HWID * CHN * 4);
  h2c*      Bf    = (h2c*)alloc((size_t)HGT * HWID * CHN * 4);
  float2*   tA    = (float2*)alloc((size_t)7 * HWID * CHN * 8);
  float2*   tB    = (float2*)alloc((size_t)7 * HWID * CHN * 8);
  if (off > ws_size) return;  // workspace too small: leaves output zero (diagnostic)

  prep_w<<<dim3(256), dim3(256), 0, stream>>>(Wma, Wpa, Wmb, Wpb, Wt);
  kfreq1<<<dim3(7 * HWID), dim3(256), 0, stream>>>(KA, KB, tA, tB);
  kfreq2<<<dim3(128 * HWID), dim3(256), 0, stream>>>(tA, tB, Af, Bf);
  pass1_fftw<<<dim3(CHN / 32, HGT, BATCH), dim3(256), 0, stream>>>(x, X1, xh);
  gemm_gates<<<dim3(8, 1024), dim3(256), 0, stream>>>(xh, Wt, bma, bpa, bmb, bpb, gates);
  pass2_col<<<dim3(CHN / 32, HWID, BATCH), dim3(256), 0, stream>>>(X1, gates, Af, Bf);
  pass3_ifftw<<<dim3(CHN / 32, HGT, BATCH), dim3(256), 0, stream>>>(X1, out);
}